// Round 13
// baseline (713.626 us; speedup 1.0000x reference)
//
#include <hip/hip_runtime.h>

typedef __attribute__((ext_vector_type(8))) short short8;
typedef __attribute__((ext_vector_type(4))) float floatx4;
typedef __attribute__((ext_vector_type(2))) unsigned int uintx2;
typedef __attribute__((ext_vector_type(4))) unsigned int uintx4;
typedef unsigned short u16;

#define MFMA(a, b, c) __builtin_amdgcn_mfma_f32_16x16x32_bf16((a), (b), (c), 0, 0, 0)
#define BAR() do { asm volatile("" ::: "memory"); __builtin_amdgcn_s_barrier(); \
                   asm volatile("" ::: "memory"); } while (0)
#define LGKM0() asm volatile("s_waitcnt lgkmcnt(0)" ::: "memory")

__device__ __forceinline__ u16 f2bf(float f) {
  unsigned int u = __builtin_bit_cast(unsigned int, f);
  u += ((u >> 16) & 1u) + 0x7fffu;
  return (u16)(u >> 16);
}

__device__ __forceinline__ float softplus_f(float v) {
  float a = __builtin_fabsf(v);
  float e = __expf(-a);
  float l = __logf(1.0f + e);
  return __builtin_fmaxf(v, 0.0f) + l;
}

__device__ __forceinline__ unsigned int pack_sp(float lo, float hi) {
  return (unsigned int)f2bf(softplus_f(lo)) | ((unsigned int)f2bf(softplus_f(hi)) << 16);
}

// out[n*K + k] = bf16(in[k*N + n]); in is K x N row-major fp32
__global__ void transpose_cvt(const float* __restrict__ in, u16* __restrict__ out, int K, int N) {
  __shared__ float tile[32][33];
  const int bn = blockIdx.x * 32, bk = blockIdx.y * 32;
  const int tx = threadIdx.x, ty = threadIdx.y;  // 32 x 8
#pragma unroll
  for (int i = 0; i < 32; i += 8)
    tile[ty + i][tx] = in[(size_t)(bk + ty + i) * N + bn + tx];
  __syncthreads();
#pragma unroll
  for (int i = 0; i < 32; i += 8)
    out[(size_t)(bn + ty + i) * K + bk + tx] = f2bf(tile[tx][ty + i]);
}

// ---------- operand image format ----------
// IMAGE[tileRow rc][t (64k)][hi (128 rows)][slot s<1024]: slot s = granule of 8 u16,
// s = r*8 + (gg ^ ((r>>1)&7)); content = src[rc*256 + hi*128 + r][t*64 + gg*8 .. +8).
// A GEMM block stages a half-tile with 2 fully-linear gld16 per thread (1 KB/wave
// contiguous). In-LDS layout identical to R12's verified kernel (frag math reused).

// build W image from wt[N][K] bf16 (strided gather -> contiguous image)
__global__ void make_wimg(const u16* __restrict__ wt, u16* __restrict__ img, int K, int H) {
  const int b = blockIdx.x;  // ((bn*H)+t)*2 + hi
  const int hi = b & 1, th = (b >> 1) % H, bn = (b >> 1) / H;
  const int tid = threadIdx.x;
#pragma unroll
  for (int j = 0; j < 2; ++j) {
    const int s = j * 512 + tid;
    const int r = s >> 3, gg = s & 7;
    const int k0 = th * 64 + ((gg ^ ((r >> 1) & 7)) << 3);
    short8 v = *(const short8*)(wt + (size_t)(bn * 256 + hi * 128 + r) * K + k0);
    *(short8*)(img + (size_t)b * 8192 + s * 8) = v;
  }
}

// x fp32 [M][256] -> bf16 act image (K=256, H=4)
__global__ void cvt_ximg(const float* __restrict__ x, u16* __restrict__ img) {
  const int b = blockIdx.x;  // mi*8 + t*2 + hi
  const int hi = b & 1, th = (b >> 1) & 3, mi = b >> 3;
  const int tid = threadIdx.x;
#pragma unroll
  for (int j = 0; j < 2; ++j) {
    const int s = j * 512 + tid;
    const int r = s >> 3, gg = s & 7;
    const int k0 = th * 64 + ((gg ^ ((r >> 1) & 7)) << 3);
    const float* p = x + (size_t)(mi * 256 + hi * 128 + r) * 256 + k0;
    floatx4 a = *(const floatx4*)p, c = *(const floatx4*)(p + 4);
    uintx4 w;
    w.x = (unsigned)f2bf(a.x) | ((unsigned)f2bf(a.y) << 16);
    w.y = (unsigned)f2bf(a.z) | ((unsigned)f2bf(a.w) << 16);
    w.z = (unsigned)f2bf(c.x) | ((unsigned)f2bf(c.y) << 16);
    w.w = (unsigned)f2bf(c.z) | ((unsigned)f2bf(c.w) << 16);
    *(uintx4*)(img + (size_t)b * 8192 + s * 8) = w;
  }
}

__device__ __forceinline__ void gld16(const void* g, void* l) {
  __builtin_amdgcn_global_load_lds((const __attribute__((address_space(1))) void*)g,
                                   (__attribute__((address_space(3))) void*)l, 16, 0, 0);
}

// ======== 256x256 GEMM on imaged operands; R12's verified 8-phase schedule ========
// EPI 0: softplus -> bf16 act-image (HOUT tiles); EPI 1: fp32 row-major C.
template <int K, int HOUT, int EPI>
__global__ __launch_bounds__(512, 2) void gemm8i(const u16* __restrict__ actimg,
                                                 const u16* __restrict__ wimg,
                                                 void* __restrict__ Cout, int N, int nbn) {
  constexpr int H = K / 64;
  __shared__ u16 lds[2 * 4 * 8192];  // [buf][Alo,Ahi,Wlo,Whi][8192] = 128 KB
  u16* L = lds;
  const int tid = threadIdx.x, lane = tid & 63, wv = tid >> 6;
  const int l15 = lane & 15, g = lane >> 4;
  const int wvm = wv >> 2, wvn = wv & 3;  // 2 x 4; wave owns 128m x 64n
  const int nwg = gridDim.x, o = blockIdx.x;
  const int sw = (o & 7) * (nwg >> 3) + (o >> 3);  // XCD swizzle (nwg % 8 == 0)
  const int bm = sw / nbn, bn = sw % nbn;

  // fragment offsets (identical to R12's verified layout)
  int afo[8], wfo[4];
#pragma unroll
  for (int mt = 0; mt < 8; ++mt) {
    const int r = mt * 16 + l15;
    afo[mt] = (r * 8 + (g ^ ((r >> 1) & 7))) * 8;
  }
#pragma unroll
  for (int nt = 0; nt < 4; ++nt) {
    const int r = (wvn & 1) * 64 + nt * 16 + l15;
    wfo[nt] = (r * 8 + (g ^ ((r >> 1) & 7))) * 8;
  }
  const int aHalf = wvm * 8192;
  const int wHalf = (2 + (wvn >> 1)) * 8192;

  const u16* ab = actimg + (size_t)bm * H * 16384;  // act tile-row base
  const u16* wb = wimg + (size_t)bn * H * 16384;    // W tile-col base

#define STG(base, tt, hi, lh)                                                        \
  { _Pragma("unroll") for (int j = 0; j < 2; ++j)                                    \
      gld16(base + ((size_t)(tt)*2 + (hi)) * 8192 + (j * 512 + tid) * 8,             \
            L + ((tt)&1) * 32768 + (lh)*8192 + (j * 512 + tid) * 8); }

  floatx4 acc[4][8];
  const floatx4 z4 = {0.f, 0.f, 0.f, 0.f};
#pragma unroll
  for (int t = 0; t < 4; ++t)
#pragma unroll
    for (int mt = 0; mt < 8; ++mt) acc[t][mt] = z4;

  // prologue: tile0 (4 halves) then tile1 A-halves; vmcnt(4) -> tile0 resident
  STG(ab, 0, 0, 0) STG(ab, 0, 1, 1) STG(wb, 0, 0, 2) STG(wb, 0, 1, 3)
  STG(ab, 1, 0, 0) STG(ab, 1, 1, 1)
  asm volatile("s_waitcnt vmcnt(4)" ::: "memory");
  BAR();

  short8 A0[8], A1[8], wf0, wf1;

#pragma unroll 1
  for (int t = 0; t < H; ++t) {
    const int cb = (t & 1) * 32768;
    // P0: A@k0 + W n01@k0; stage W-lo(t+1)
#pragma unroll
    for (int mt = 0; mt < 8; ++mt) A0[mt] = *(const short8*)(L + cb + aHalf + afo[mt]);
    wf0 = *(const short8*)(L + cb + wHalf + wfo[0]);
    wf1 = *(const short8*)(L + cb + wHalf + wfo[1]);
    if (t + 1 < H) STG(wb, t + 1, 0, 2)
    BAR(); LGKM0();
    __builtin_amdgcn_s_setprio(1);
#pragma unroll
    for (int mt = 0; mt < 8; ++mt) {
      acc[0][mt] = MFMA(wf0, A0[mt], acc[0][mt]);
      acc[1][mt] = MFMA(wf1, A0[mt], acc[1][mt]);
    }
    __builtin_amdgcn_s_setprio(0);
    BAR();
    // P1: A@k32 + W n01@k32; stage W-hi(t+1)
#pragma unroll
    for (int mt = 0; mt < 8; ++mt) A1[mt] = *(const short8*)(L + cb + aHalf + (afo[mt] ^ 32));
    wf0 = *(const short8*)(L + cb + wHalf + (wfo[0] ^ 32));
    wf1 = *(const short8*)(L + cb + wHalf + (wfo[1] ^ 32));
    if (t + 1 < H) STG(wb, t + 1, 1, 3)
    BAR(); LGKM0();
    __builtin_amdgcn_s_setprio(1);
#pragma unroll
    for (int mt = 0; mt < 8; ++mt) {
      acc[0][mt] = MFMA(wf0, A1[mt], acc[0][mt]);
      acc[1][mt] = MFMA(wf1, A1[mt], acc[1][mt]);
    }
    __builtin_amdgcn_s_setprio(0);
    BAR();
    // P2: W n23@k0; stage A-lo(t+2); reuse A0
    wf0 = *(const short8*)(L + cb + wHalf + wfo[2]);
    wf1 = *(const short8*)(L + cb + wHalf + wfo[3]);
    if (t + 2 < H) STG(ab, t + 2, 0, 0)
    BAR(); LGKM0();
    __builtin_amdgcn_s_setprio(1);
#pragma unroll
    for (int mt = 0; mt < 8; ++mt) {
      acc[2][mt] = MFMA(wf0, A0[mt], acc[2][mt]);
      acc[3][mt] = MFMA(wf1, A0[mt], acc[3][mt]);
    }
    __builtin_amdgcn_s_setprio(0);
    BAR();
    // P3: W n23@k32; stage A-hi(t+2); counted vmcnt; reuse A1
    wf0 = *(const short8*)(L + cb + wHalf + (wfo[2] ^ 32));
    wf1 = *(const short8*)(L + cb + wHalf + (wfo[3] ^ 32));
    if (t + 2 < H) STG(ab, t + 2, 1, 1)
    if (t < H - 2) asm volatile("s_waitcnt vmcnt(4)" ::: "memory");
    else if (t == H - 2) asm volatile("s_waitcnt vmcnt(0)" ::: "memory");
    BAR(); LGKM0();
    __builtin_amdgcn_s_setprio(1);
#pragma unroll
    for (int mt = 0; mt < 8; ++mt) {
      acc[2][mt] = MFMA(wf0, A1[mt], acc[2][mt]);
      acc[3][mt] = MFMA(wf1, A1[mt], acc[3][mt]);
    }
    __builtin_amdgcn_s_setprio(0);
    BAR();
  }
#undef STG

  __syncthreads();  // loop drained; LDS reusable

  if constexpr (EPI == 0) {
    // pass-1: softplus -> bf16, assemble [256m][256n] in LDS (n-chunk XOR swizzle)
    u16* cl = L;
#pragma unroll
    for (int t = 0; t < 4; ++t)
#pragma unroll
      for (int mt = 0; mt < 8; ++mt) {
        const int m = wvm * 128 + mt * 16 + l15;
        const int n0 = wvn * 64 + t * 16 + g * 4;
        const int j = n0 >> 3, hh = (n0 >> 2) & 1;
        uintx2 pk;
        pk.x = pack_sp(acc[t][mt].x, acc[t][mt].y);
        pk.y = pack_sp(acc[t][mt].z, acc[t][mt].w);
        *(uintx2*)(cl + m * 256 + ((j ^ (m & 7)) << 3) + (hh << 2)) = pk;
      }
    __syncthreads();
    // pass-2: emit as act-image for the next GEMM (contiguous 8 KB streams)
    u16* outp = (u16*)Cout;
#pragma unroll
    for (int i = 0; i < 16; ++i) {
      const int idx = i * 512 + tid;       // (t3<4, hi<2, s<1024)
      const int t3 = idx >> 11, hi2 = (idx >> 10) & 1, s = idx & 1023;
      const int r = s >> 3, gg = s & 7;
      const int k64 = (gg ^ ((r >> 1) & 7)) << 3;
      const int m = hi2 * 128 + r;
      const int j = t3 * 8 + (k64 >> 3);
      uintx4 v = *(const uintx4*)(cl + m * 256 + ((j ^ (m & 7)) << 3));
      *(uintx4*)(outp + ((size_t)(bm * HOUT + bn * 4 + t3) * 2 + hi2) * 8192 + s * 8) = v;
    }
  } else {
    // fp32 C row-major in two 128-row passes
    float* cf = (float*)L;
#pragma unroll
    for (int q = 0; q < 2; ++q) {
      if (q) __syncthreads();
      if (wvm == q) {
#pragma unroll
        for (int t = 0; t < 4; ++t)
#pragma unroll
          for (int mt = 0; mt < 8; ++mt) {
            const int m = mt * 16 + l15;
            const int p = (wvn * 64 + t * 16 + g * 4) >> 1;
            *(floatx4*)(cf + m * 256 + ((p ^ ((m & 7) << 1)) << 1)) = acc[t][mt];
          }
      }
      __syncthreads();
      float* outp = (float*)Cout;
#pragma unroll
      for (int i = 0; i < 16; ++i) {
        const int c = i * 512 + tid;
        const int m = c >> 6, cc = c & 63;
        const int p = cc * 2;
        floatx4 v = *(const floatx4*)(cf + m * 256 + ((p ^ ((m & 7) << 1)) << 1));
        *(floatx4*)(outp + ((size_t)blockIdx.x * 0 + ((size_t)( (sw) / nbn) * 256 + q * 128 + m)) * N + (size_t)(sw % nbn) * 256 + cc * 4) = v;
      }
    }
  }
}

// ---------------- fallback: R1 fused kernel (ws too small) ----------------
__global__ __launch_bounds__(512, 2) void mlp3_fused(const float* __restrict__ x,
                                                     const u16* __restrict__ w1t,
                                                     const u16* __restrict__ w2t,
                                                     const u16* __restrict__ w3t,
                                                     float* __restrict__ out) {
  __shared__ u16 h1s[64 * 1024];
  __shared__ u16 xs[64 * 256];
  const int tid = threadIdx.x, lane = tid & 63, wv = tid >> 6;
  const int l15 = lane & 15, g = lane >> 4;
  const size_t m0 = (size_t)blockIdx.x * 64;
  const floatx4 z4 = {0.f, 0.f, 0.f, 0.f};
  {
    const float* xp = x + m0 * 256;
#pragma unroll
    for (int r = 0; r < 8; ++r) {
      int idx4 = r * 512 + tid;
      int m = idx4 >> 6, k = (idx4 & 63) << 2;
      floatx4 v = *(const floatx4*)(xp + m * 256 + k);
      uintx2 pk;
      pk.x = (unsigned)f2bf(v.x) | ((unsigned)f2bf(v.y) << 16);
      pk.y = (unsigned)f2bf(v.z) | ((unsigned)f2bf(v.w) << 16);
      *(uintx2*)(xs + ((m * 256 + k) ^ ((m & 7) << 3))) = pk;
    }
  }
  __syncthreads();
#pragma unroll 1
  for (int c = 0; c < 4; ++c) {
    floatx4 acc[2][4];
#pragma unroll
    for (int t = 0; t < 2; ++t)
#pragma unroll
      for (int mt = 0; mt < 4; ++mt) acc[t][mt] = z4;
    const u16* p0 = w1t + (size_t)(c * 256 + wv * 32 + l15) * 256;
#pragma unroll
    for (int ks = 0; ks < 8; ++ks) {
      const int k = ks * 32 + g * 8;
      short8 a0 = *(const short8*)(p0 + k);
      short8 a1 = *(const short8*)(p0 + 16 * 256 + k);
      short8 b0 = *(const short8*)(xs + (((0 * 16 + l15) * 256 + k) ^ ((l15 & 7) << 3)));
      short8 b1 = *(const short8*)(xs + (((1 * 16 + l15) * 256 + k) ^ ((l15 & 7) << 3)));
      short8 b2 = *(const short8*)(xs + (((2 * 16 + l15) * 256 + k) ^ ((l15 & 7) << 3)));
      short8 b3 = *(const short8*)(xs + (((3 * 16 + l15) * 256 + k) ^ ((l15 & 7) << 3)));
      acc[0][0] = MFMA(a0, b0, acc[0][0]); acc[0][1] = MFMA(a0, b1, acc[0][1]);
      acc[0][2] = MFMA(a0, b2, acc[0][2]); acc[0][3] = MFMA(a0, b3, acc[0][3]);
      acc[1][0] = MFMA(a1, b0, acc[1][0]); acc[1][1] = MFMA(a1, b1, acc[1][1]);
      acc[1][2] = MFMA(a1, b2, acc[1][2]); acc[1][3] = MFMA(a1, b3, acc[1][3]);
    }
#pragma unroll
    for (int t = 0; t < 2; ++t)
#pragma unroll
      for (int mt = 0; mt < 4; ++mt) {
        const int n1 = c * 256 + wv * 32 + t * 16 + g * 4;
        const int m = mt * 16 + l15;
        uintx2 pk;
        pk.x = pack_sp(acc[t][mt].x, acc[t][mt].y);
        pk.y = pack_sp(acc[t][mt].z, acc[t][mt].w);
        *(uintx2*)(h1s + ((m * 1024 + n1) ^ ((m & 7) << 3))) = pk;
      }
  }
  __syncthreads();
  floatx4 acc3[2][4];
#pragma unroll
  for (int t = 0; t < 2; ++t)
#pragma unroll
    for (int mt = 0; mt < 4; ++mt) acc3[t][mt] = z4;
#pragma unroll 1
  for (int c2 = 0; c2 < 4; ++c2) {
    floatx4 acc2[2][4];
#pragma unroll
    for (int t = 0; t < 2; ++t)
#pragma unroll
      for (int mt = 0; mt < 4; ++mt) acc2[t][mt] = z4;
    {
      const u16* p0 = w2t + (size_t)(c2 * 256 + wv * 32 + l15) * 1024;
#pragma unroll 4
      for (int ks = 0; ks < 32; ++ks) {
        const int k = ks * 32 + g * 8;
        short8 a0 = *(const short8*)(p0 + k);
        short8 a1 = *(const short8*)(p0 + 16 * 1024 + k);
        short8 b0 = *(const short8*)(h1s + (((0 * 16 + l15) * 1024 + k) ^ ((l15 & 7) << 3)));
        short8 b1 = *(const short8*)(h1s + (((1 * 16 + l15) * 1024 + k) ^ ((l15 & 7) << 3)));
        short8 b2 = *(const short8*)(h1s + (((2 * 16 + l15) * 1024 + k) ^ ((l15 & 7) << 3)));
        short8 b3 = *(const short8*)(h1s + (((3 * 16 + l15) * 1024 + k) ^ ((l15 & 7) << 3)));
        acc2[0][0] = MFMA(a0, b0, acc2[0][0]); acc2[0][1] = MFMA(a0, b1, acc2[0][1]);
        acc2[0][2] = MFMA(a0, b2, acc2[0][2]); acc2[0][3] = MFMA(a0, b3, acc2[0][3]);
        acc2[1][0] = MFMA(a1, b0, acc2[1][0]); acc2[1][1] = MFMA(a1, b1, acc2[1][1]);
        acc2[1][2] = MFMA(a1, b2, acc2[1][2]); acc2[1][3] = MFMA(a1, b3, acc2[1][3]);
      }
    }
    __syncthreads();
#pragma unroll
    for (int t = 0; t < 2; ++t)
#pragma unroll
      for (int mt = 0; mt < 4; ++mt) {
        const int n2l = wv * 32 + t * 16 + g * 4;
        const int m = mt * 16 + l15;
        uintx2 pk;
        pk.x = pack_sp(acc2[t][mt].x, acc2[t][mt].y);
        pk.y = pack_sp(acc2[t][mt].z, acc2[t][mt].w);
        *(uintx2*)(xs + ((m * 256 + n2l) ^ ((m & 7) << 3))) = pk;
      }
    __syncthreads();
    {
      const u16* p0 = w3t + (size_t)(wv * 32 + l15) * 1024 + c2 * 256;
#pragma unroll
      for (int ks = 0; ks < 8; ++ks) {
        const int k = ks * 32 + g * 8;
        short8 a0 = *(const short8*)(p0 + k);
        short8 a1 = *(const short8*)(p0 + 16 * 1024 + k);
        short8 b0 = *(const short8*)(xs + (((0 * 16 + l15) * 256 + k) ^ ((l15 & 7) << 3)));
        short8 b1 = *(const short8*)(xs + (((1 * 16 + l15) * 256 + k) ^ ((l15 & 7) << 3)));
        short8 b2 = *(const short8*)(xs + (((2 * 16 + l15) * 256 + k) ^ ((l15 & 7) << 3)));
        short8 b3 = *(const short8*)(xs + (((3 * 16 + l15) * 256 + k) ^ ((l15 & 7) << 3)));
        acc3[0][0] = MFMA(a0, b0, acc3[0][0]); acc3[0][1] = MFMA(a0, b1, acc3[0][1]);
        acc3[0][2] = MFMA(a0, b2, acc3[0][2]); acc3[0][3] = MFMA(a0, b3, acc3[0][3]);
        acc3[1][0] = MFMA(a1, b0, acc3[1][0]); acc3[1][1] = MFMA(a1, b1, acc3[1][1]);
        acc3[1][2] = MFMA(a1, b2, acc3[1][2]); acc3[1][3] = MFMA(a1, b3, acc3[1][3]);
      }
    }
  }
#pragma unroll
  for (int t = 0; t < 2; ++t)
#pragma unroll
    for (int mt = 0; mt < 4; ++mt) {
      const int n3 = wv * 32 + t * 16 + g * 4;
      const int m = mt * 16 + l15;
      *(floatx4*)(out + (m0 + m) * 256 + n3) = acc3[t][mt];
    }
}

extern "C" void kernel_launch(void* const* d_in, const int* in_sizes, int n_in,
                              void* d_out, int out_size, void* d_ws, size_t ws_size,
                              hipStream_t stream) {
  const float* x = (const float*)d_in[0];
  const float* w1 = (const float*)d_in[1];
  const float* w2 = (const float*)d_in[2];
  const float* w3 = (const float*)d_in[3];
  float* out = (float*)d_out;
  const size_t M = 131072;

  // image layout (u16 units)
  u16* wimg1 = (u16*)d_ws;               // 4*4*2*8192   = 256K
  u16* wimg2 = wimg1 + 262144;           // 4*16*2*8192  = 1M
  u16* wimg3 = wimg2 + 1048576;          // 1*16*2*8192  = 256K
  u16* ximg = wimg3 + 262144;            // CM*256
  // h1img = ximg + CM*256 (CM*1024); h2img after that (CM*1024); tmp aliases ximg

  size_t CM = 0;
  const size_t cands[4] = {32768, 16384, 8192, 4096};
  for (int i = 0; i < 4; ++i) {
    size_t need = ((size_t)1572864 + cands[i] * 2304) * sizeof(u16);
    if (ws_size >= need) { CM = cands[i]; break; }
  }

  dim3 tb(32, 8);
  if (CM) {
    u16* h1img = ximg + CM * 256;
    u16* h2img = h1img + CM * 1024;
    u16* tmp = ximg;  // weight-prep scratch, dead before ximg is written
    // weight prep: transpose to [N][K] bf16, then image-ify
    transpose_cvt<<<dim3(32, 8), tb, 0, stream>>>(w1, tmp, 256, 1024);
    make_wimg<<<32, 512, 0, stream>>>(tmp, wimg1, 256, 4);
    transpose_cvt<<<dim3(32, 32), tb, 0, stream>>>(w2, tmp, 1024, 1024);
    make_wimg<<<128, 512, 0, stream>>>(tmp, wimg2, 1024, 16);
    transpose_cvt<<<dim3(8, 32), tb, 0, stream>>>(w3, tmp, 1024, 256);
    make_wimg<<<32, 512, 0, stream>>>(tmp, wimg3, 1024, 16);

    const int nchunk = (int)(M / CM);
    for (int ci = 0; ci < nchunk; ++ci) {
      const float* xc = x + (size_t)ci * CM * 256;
      float* oc = out + (size_t)ci * CM * 256;
      cvt_ximg<<<(int)(CM / 256) * 8, 512, 0, stream>>>(xc, ximg);
      gemm8i<256, 16, 0><<<(int)(CM / 256) * 4, 512, 0, stream>>>(ximg, wimg1, h1img, 1024, 4);
      gemm8i<1024, 16, 0><<<(int)(CM / 256) * 4, 512, 0, stream>>>(h1img, wimg2, h2img, 1024, 4);
      gemm8i<1024, 0, 1><<<(int)(CM / 256), 512, 0, stream>>>(h2img, wimg3, oc, 256, 1);
    }
  } else {
    u16* w1t = (u16*)d_ws;
    u16* w2t = w1t + 1024 * 256;
    u16* w3t = w2t + 1024 * 1024;
    transpose_cvt<<<dim3(32, 8), tb, 0, stream>>>(w1, w1t, 256, 1024);
    transpose_cvt<<<dim3(32, 32), tb, 0, stream>>>(w2, w2t, 1024, 1024);
    transpose_cvt<<<dim3(8, 32), tb, 0, stream>>>(w3, w3t, 1024, 256);
    mlp3_fused<<<M / 64, 512, 0, stream>>>(x, w1t, w2t, w3t, out);
  }
}

// Round 14
// 661.903 us; speedup vs baseline: 1.0781x; 1.0781x over previous
//
#include <hip/hip_runtime.h>

typedef __attribute__((ext_vector_type(8))) short short8;
typedef __attribute__((ext_vector_type(4))) float floatx4;
typedef __attribute__((ext_vector_type(2))) unsigned int uintx2;
typedef __attribute__((ext_vector_type(4))) unsigned int uintx4;
typedef unsigned short u16;

#define MFMA(a, b, c) __builtin_amdgcn_mfma_f32_16x16x32_bf16((a), (b), (c), 0, 0, 0)
#define BAR() do { asm volatile("" ::: "memory"); __builtin_amdgcn_s_barrier(); \
                   asm volatile("" ::: "memory"); } while (0)
#define LGKM0() asm volatile("s_waitcnt lgkmcnt(0)" ::: "memory")

__device__ __forceinline__ u16 f2bf(float f) {
  unsigned int u = __builtin_bit_cast(unsigned int, f);
  u += ((u >> 16) & 1u) + 0x7fffu;
  return (u16)(u >> 16);
}

__device__ __forceinline__ float softplus_f(float v) {
  float a = __builtin_fabsf(v);
  float e = __expf(-a);
  float l = __logf(1.0f + e);
  return __builtin_fmaxf(v, 0.0f) + l;
}

__device__ __forceinline__ unsigned int pack_sp(float lo, float hi) {
  return (unsigned int)f2bf(softplus_f(lo)) | ((unsigned int)f2bf(softplus_f(hi)) << 16);
}

// out[n*K + k] = bf16(in[k*N + n]); in is K x N row-major fp32
__global__ void transpose_cvt(const float* __restrict__ in, u16* __restrict__ out, int K, int N) {
  __shared__ float tile[32][33];
  const int bn = blockIdx.x * 32, bk = blockIdx.y * 32;
  const int tx = threadIdx.x, ty = threadIdx.y;  // 32 x 8
#pragma unroll
  for (int i = 0; i < 32; i += 8)
    tile[ty + i][tx] = in[(size_t)(bk + ty + i) * N + bn + tx];
  __syncthreads();
#pragma unroll
  for (int i = 0; i < 32; i += 8)
    out[(size_t)(bn + ty + i) * K + bk + tx] = f2bf(tile[tx][ty + i]);
}

__device__ __forceinline__ void gld16(const void* g, void* l) {
  __builtin_amdgcn_global_load_lds((const __attribute__((address_space(1))) void*)g,
                                   (__attribute__((address_space(3))) void*)l, 16, 0, 0);
}

template <int LN>
__device__ __forceinline__ void vwait() {
  if constexpr (LN == 0) asm volatile("s_waitcnt vmcnt(0)" ::: "memory");
  else if constexpr (LN == 2) asm volatile("s_waitcnt vmcnt(2)" ::: "memory");
  else if constexpr (LN == 3) asm volatile("s_waitcnt vmcnt(3)" ::: "memory");
}

// ===== 128x256 GEMM (C = act @ wt^T), BK=32, 48 KB LDS, 2 blocks/CU =====
// Designed for the 128-VGPR cap (acc[4][4]=64 + 8 frags*4 + addr ~ 116 real).
// Half layout: slot(r,gg) = r*4 + (gg ^ ((r>>1)&3)); b128 frag reads at the
// wave64 bank floor; staging 64B-coalesced (A: 1 gld16/thread, W: 2).
// Per step: {stage(h+1) -> counted vwait -> BAR -> 8 frag reads -> 16 MFMA -> BAR}.
// Two resident blocks per CU give the matrix pipe a second feeder while the
// other block sits in its stage/barrier section.
template <int K, int EPI, bool ACTF32>
__global__ __launch_bounds__(512, 4) void gemm2b(const void* __restrict__ actv,
                                                 const u16* __restrict__ wt,
                                                 void* __restrict__ Cout, int N, int nbn) {
  constexpr int H = K / 32;
  constexpr int BUF = 12288;  // u16 per buffer: A 4096 + W 8192 (24 KB); x2 = 48 KB
  __shared__ u16 lds[2 * BUF];
  u16* L = lds;
  const int tid = threadIdx.x, lane = tid & 63, wv = tid >> 6;
  const int l15 = lane & 15, g = lane >> 4;
  const int wvm = wv >> 2, wvn = wv & 3;  // 2 x 4; wave owns 64m x 64n
  const int nwg = gridDim.x, o = blockIdx.x;
  const int sw = (o & 7) * (nwg >> 3) + (o >> 3);  // XCD swizzle (nwg % 8 == 0)
  const int bm = sw / nbn, bn = sw % nbn;
  const size_t am0 = (size_t)bm * 128;
  const size_t wn0 = (size_t)bn * 256;

  // fragment offsets (u16 units within a buffer)
  int afo[4], wfo[4];
#pragma unroll
  for (int mt = 0; mt < 4; ++mt) {
    const int r = wvm * 64 + mt * 16 + l15;
    afo[mt] = (r * 4 + (g ^ ((r >> 1) & 3))) * 8;
  }
#pragma unroll
  for (int nt = 0; nt < 4; ++nt) {
    const int r = wvn * 64 + nt * 16 + l15;
    wfo[nt] = 4096 + (r * 4 + (g ^ ((r >> 1) & 3))) * 8;
  }

  // stage addressing
  const int rA = tid >> 2, gA = (tid & 3) ^ ((rA >> 1) & 3);
  const int rW1 = 128 + rA, gW1 = (tid & 3) ^ ((rW1 >> 1) & 3);
  const u16* asrc = nullptr;
  const float* fsrc = nullptr;
  if constexpr (ACTF32) fsrc = (const float*)actv + (am0 + rA) * K + gA * 8;
  else asrc = (const u16*)actv + (am0 + rA) * K + gA * 8;
  const u16* wsrc0 = wt + (wn0 + rA) * K + gA * 8;
  const u16* wsrc1 = wt + (wn0 + rW1) * K + gW1 * 8;
  const int dA = tid * 8, dW0 = 4096 + tid * 8, dW1 = 4096 + (512 + tid) * 8;

#define STG_W(hh)                                                       \
  { gld16(wsrc0 + (hh) * 32, L + ((hh) & 1) * BUF + dW0);               \
    gld16(wsrc1 + (hh) * 32, L + ((hh) & 1) * BUF + dW1); }
#define STG_AB(hh) { gld16(asrc + (hh) * 32, L + ((hh) & 1) * BUF + dA); }
#define STG_AF(hh)                                                      \
  { floatx4 v0 = *(const floatx4*)(fsrc + (hh) * 32);                   \
    floatx4 v1 = *(const floatx4*)(fsrc + (hh) * 32 + 4);               \
    uintx4 w_;                                                          \
    w_.x = (unsigned)f2bf(v0.x) | ((unsigned)f2bf(v0.y) << 16);         \
    w_.y = (unsigned)f2bf(v0.z) | ((unsigned)f2bf(v0.w) << 16);         \
    w_.z = (unsigned)f2bf(v1.x) | ((unsigned)f2bf(v1.y) << 16);         \
    w_.w = (unsigned)f2bf(v1.z) | ((unsigned)f2bf(v1.w) << 16);         \
    *(uintx4*)(L + ((hh) & 1) * BUF + dA) = w_; }

  floatx4 acc[4][4];
  const floatx4 z4 = {0.f, 0.f, 0.f, 0.f};
#pragma unroll
  for (int nt = 0; nt < 4; ++nt)
#pragma unroll
    for (int mt = 0; mt < 4; ++mt) acc[nt][mt] = z4;

  // prologue: stage step 0
  if constexpr (ACTF32) { STG_AF(0) STG_W(0) }
  else { STG_AB(0) STG_W(0) }

#pragma unroll 1
  for (int h = 0; h < H; ++h) {
    const int cb = (h & 1) * BUF;
    if (h + 1 < H) {
      if constexpr (ACTF32) { STG_AF(h + 1) STG_W(h + 1) LGKM0(); vwait<2>(); }
      else { STG_AB(h + 1) STG_W(h + 1) vwait<3>(); }
    } else {
      if constexpr (ACTF32) LGKM0();
      vwait<0>();
    }
    BAR();
    short8 af0 = *(const short8*)(L + cb + afo[0]);
    short8 af1 = *(const short8*)(L + cb + afo[1]);
    short8 af2 = *(const short8*)(L + cb + afo[2]);
    short8 af3 = *(const short8*)(L + cb + afo[3]);
    short8 wf0 = *(const short8*)(L + cb + wfo[0]);
    short8 wf1 = *(const short8*)(L + cb + wfo[1]);
    short8 wf2 = *(const short8*)(L + cb + wfo[2]);
    short8 wf3 = *(const short8*)(L + cb + wfo[3]);
    __builtin_amdgcn_s_setprio(1);
    acc[0][0] = MFMA(wf0, af0, acc[0][0]);
    acc[0][1] = MFMA(wf0, af1, acc[0][1]);
    acc[0][2] = MFMA(wf0, af2, acc[0][2]);
    acc[0][3] = MFMA(wf0, af3, acc[0][3]);
    acc[1][0] = MFMA(wf1, af0, acc[1][0]);
    acc[1][1] = MFMA(wf1, af1, acc[1][1]);
    acc[1][2] = MFMA(wf1, af2, acc[1][2]);
    acc[1][3] = MFMA(wf1, af3, acc[1][3]);
    acc[2][0] = MFMA(wf2, af0, acc[2][0]);
    acc[2][1] = MFMA(wf2, af1, acc[2][1]);
    acc[2][2] = MFMA(wf2, af2, acc[2][2]);
    acc[2][3] = MFMA(wf2, af3, acc[2][3]);
    acc[3][0] = MFMA(wf3, af0, acc[3][0]);
    acc[3][1] = MFMA(wf3, af1, acc[3][1]);
    acc[3][2] = MFMA(wf3, af2, acc[3][2]);
    acc[3][3] = MFMA(wf3, af3, acc[3][3]);
    __builtin_amdgcn_s_setprio(0);
    BAR();
  }
#undef STG_W
#undef STG_AB
#undef STG_AF

  __syncthreads();  // loop drained; LDS reusable

  if constexpr (EPI == 0) {
    // softplus -> bf16 C via LDS transpose; two 64-row passes (32 KB each)
    u16* cl = L;
#pragma unroll
    for (int q = 0; q < 2; ++q) {
      if (q) __syncthreads();
      if (wvm == q) {
#pragma unroll
        for (int nt = 0; nt < 4; ++nt)
#pragma unroll
          for (int mt = 0; mt < 4; ++mt) {
            const int m = mt * 16 + l15;  // 0..63
            const int n0 = wvn * 64 + nt * 16 + g * 4;
            const int j = n0 >> 3, hh = (n0 >> 2) & 1;
            uintx2 pk;
            pk.x = pack_sp(acc[nt][mt].x, acc[nt][mt].y);
            pk.y = pack_sp(acc[nt][mt].z, acc[nt][mt].w);
            *(uintx2*)(cl + m * 256 + ((j ^ (m & 7)) << 3) + (hh << 2)) = pk;
          }
      }
      __syncthreads();
      u16* outp = (u16*)Cout;
#pragma unroll
      for (int i = 0; i < 4; ++i) {
        const int c = i * 512 + tid;  // 16B chunk; 32/row, 64 rows
        const int m = c >> 5, j = c & 31;
        uintx4 v = *(const uintx4*)(cl + m * 256 + ((j ^ (m & 7)) << 3));
        *(uintx4*)(outp + (am0 + q * 64 + m) * N + wn0 + j * 8) = v;
      }
    }
  } else {
    // fp32 C in four 32-row passes (32 KB each)
    float* cf = (float*)L;
#pragma unroll
    for (int q = 0; q < 4; ++q) {
      if (q) __syncthreads();
      if (wvm == (q >> 1)) {
#pragma unroll
        for (int nt = 0; nt < 4; ++nt)
#pragma unroll
          for (int mt2 = 0; mt2 < 2; ++mt2) {
            const int mt = (q & 1) * 2 + mt2;
            const int m = mt2 * 16 + l15;  // 0..31
            const int p = (wvn * 64 + nt * 16 + g * 4) >> 1;
            *(floatx4*)(cf + m * 256 + ((p ^ ((m & 7) << 1)) << 1)) = acc[nt][mt];
          }
      }
      __syncthreads();
      float* outp = (float*)Cout;
#pragma unroll
      for (int i = 0; i < 4; ++i) {
        const int c = i * 512 + tid;  // 16B chunk; 64/row, 32 rows
        const int m = c >> 6, cc = c & 63;
        const int p = cc * 2;
        floatx4 v = *(const floatx4*)(cf + m * 256 + ((p ^ ((m & 7) << 1)) << 1));
        *(floatx4*)(outp + (am0 + q * 32 + m) * N + wn0 + cc * 4) = v;
      }
    }
  }
}

// ---------------- fallback: R1 fused kernel (ws too small) ----------------
__global__ __launch_bounds__(512, 2) void mlp3_fused(const float* __restrict__ x,
                                                     const u16* __restrict__ w1t,
                                                     const u16* __restrict__ w2t,
                                                     const u16* __restrict__ w3t,
                                                     float* __restrict__ out) {
  __shared__ u16 h1s[64 * 1024];
  __shared__ u16 xs[64 * 256];
  const int tid = threadIdx.x, lane = tid & 63, wv = tid >> 6;
  const int l15 = lane & 15, g = lane >> 4;
  const size_t m0 = (size_t)blockIdx.x * 64;
  const floatx4 z4 = {0.f, 0.f, 0.f, 0.f};
  {
    const float* xp = x + m0 * 256;
#pragma unroll
    for (int r = 0; r < 8; ++r) {
      int idx4 = r * 512 + tid;
      int m = idx4 >> 6, k = (idx4 & 63) << 2;
      floatx4 v = *(const floatx4*)(xp + m * 256 + k);
      uintx2 pk;
      pk.x = (unsigned)f2bf(v.x) | ((unsigned)f2bf(v.y) << 16);
      pk.y = (unsigned)f2bf(v.z) | ((unsigned)f2bf(v.w) << 16);
      *(uintx2*)(xs + ((m * 256 + k) ^ ((m & 7) << 3))) = pk;
    }
  }
  __syncthreads();
#pragma unroll 1
  for (int c = 0; c < 4; ++c) {
    floatx4 acc[2][4];
#pragma unroll
    for (int t = 0; t < 2; ++t)
#pragma unroll
      for (int mt = 0; mt < 4; ++mt) acc[t][mt] = z4;
    const u16* p0 = w1t + (size_t)(c * 256 + wv * 32 + l15) * 256;
#pragma unroll
    for (int ks = 0; ks < 8; ++ks) {
      const int k = ks * 32 + g * 8;
      short8 a0 = *(const short8*)(p0 + k);
      short8 a1 = *(const short8*)(p0 + 16 * 256 + k);
      short8 b0 = *(const short8*)(xs + (((0 * 16 + l15) * 256 + k) ^ ((l15 & 7) << 3)));
      short8 b1 = *(const short8*)(xs + (((1 * 16 + l15) * 256 + k) ^ ((l15 & 7) << 3)));
      short8 b2 = *(const short8*)(xs + (((2 * 16 + l15) * 256 + k) ^ ((l15 & 7) << 3)));
      short8 b3 = *(const short8*)(xs + (((3 * 16 + l15) * 256 + k) ^ ((l15 & 7) << 3)));
      acc[0][0] = MFMA(a0, b0, acc[0][0]); acc[0][1] = MFMA(a0, b1, acc[0][1]);
      acc[0][2] = MFMA(a0, b2, acc[0][2]); acc[0][3] = MFMA(a0, b3, acc[0][3]);
      acc[1][0] = MFMA(a1, b0, acc[1][0]); acc[1][1] = MFMA(a1, b1, acc[1][1]);
      acc[1][2] = MFMA(a1, b2, acc[1][2]); acc[1][3] = MFMA(a1, b3, acc[1][3]);
    }
#pragma unroll
    for (int t = 0; t < 2; ++t)
#pragma unroll
      for (int mt = 0; mt < 4; ++mt) {
        const int n1 = c * 256 + wv * 32 + t * 16 + g * 4;
        const int m = mt * 16 + l15;
        uintx2 pk;
        pk.x = pack_sp(acc[t][mt].x, acc[t][mt].y);
        pk.y = pack_sp(acc[t][mt].z, acc[t][mt].w);
        *(uintx2*)(h1s + ((m * 1024 + n1) ^ ((m & 7) << 3))) = pk;
      }
  }
  __syncthreads();
  floatx4 acc3[2][4];
#pragma unroll
  for (int t = 0; t < 2; ++t)
#pragma unroll
    for (int mt = 0; mt < 4; ++mt) acc3[t][mt] = z4;
#pragma unroll 1
  for (int c2 = 0; c2 < 4; ++c2) {
    floatx4 acc2[2][4];
#pragma unroll
    for (int t = 0; t < 2; ++t)
#pragma unroll
      for (int mt = 0; mt < 4; ++mt) acc2[t][mt] = z4;
    {
      const u16* p0 = w2t + (size_t)(c2 * 256 + wv * 32 + l15) * 1024;
#pragma unroll 4
      for (int ks = 0; ks < 32; ++ks) {
        const int k = ks * 32 + g * 8;
        short8 a0 = *(const short8*)(p0 + k);
        short8 a1 = *(const short8*)(p0 + 16 * 1024 + k);
        short8 b0 = *(const short8*)(h1s + (((0 * 16 + l15) * 1024 + k) ^ ((l15 & 7) << 3)));
        short8 b1 = *(const short8*)(h1s + (((1 * 16 + l15) * 1024 + k) ^ ((l15 & 7) << 3)));
        short8 b2 = *(const short8*)(h1s + (((2 * 16 + l15) * 1024 + k) ^ ((l15 & 7) << 3)));
        short8 b3 = *(const short8*)(h1s + (((3 * 16 + l15) * 1024 + k) ^ ((l15 & 7) << 3)));
        acc2[0][0] = MFMA(a0, b0, acc2[0][0]); acc2[0][1] = MFMA(a0, b1, acc2[0][1]);
        acc2[0][2] = MFMA(a0, b2, acc2[0][2]); acc2[0][3] = MFMA(a0, b3, acc2[0][3]);
        acc2[1][0] = MFMA(a1, b0, acc2[1][0]); acc2[1][1] = MFMA(a1, b1, acc2[1][1]);
        acc2[1][2] = MFMA(a1, b2, acc2[1][2]); acc2[1][3] = MFMA(a1, b3, acc2[1][3]);
      }
    }
    __syncthreads();
#pragma unroll
    for (int t = 0; t < 2; ++t)
#pragma unroll
      for (int mt = 0; mt < 4; ++mt) {
        const int n2l = wv * 32 + t * 16 + g * 4;
        const int m = mt * 16 + l15;
        uintx2 pk;
        pk.x = pack_sp(acc2[t][mt].x, acc2[t][mt].y);
        pk.y = pack_sp(acc2[t][mt].z, acc2[t][mt].w);
        *(uintx2*)(xs + ((m * 256 + n2l) ^ ((m & 7) << 3))) = pk;
      }
    __syncthreads();
    {
      const u16* p0 = w3t + (size_t)(wv * 32 + l15) * 1024 + c2 * 256;
#pragma unroll
      for (int ks = 0; ks < 8; ++ks) {
        const int k = ks * 32 + g * 8;
        short8 a0 = *(const short8*)(p0 + k);
        short8 a1 = *(const short8*)(p0 + 16 * 1024 + k);
        short8 b0 = *(const short8*)(xs + (((0 * 16 + l15) * 256 + k) ^ ((l15 & 7) << 3)));
        short8 b1 = *(const short8*)(xs + (((1 * 16 + l15) * 256 + k) ^ ((l15 & 7) << 3)));
        short8 b2 = *(const short8*)(xs + (((2 * 16 + l15) * 256 + k) ^ ((l15 & 7) << 3)));
        short8 b3 = *(const short8*)(xs + (((3 * 16 + l15) * 256 + k) ^ ((l15 & 7) << 3)));
        acc3[0][0] = MFMA(a0, b0, acc3[0][0]); acc3[0][1] = MFMA(a0, b1, acc3[0][1]);
        acc3[0][2] = MFMA(a0, b2, acc3[0][2]); acc3[0][3] = MFMA(a0, b3, acc3[0][3]);
        acc3[1][0] = MFMA(a1, b0, acc3[1][0]); acc3[1][1] = MFMA(a1, b1, acc3[1][1]);
        acc3[1][2] = MFMA(a1, b2, acc3[1][2]); acc3[1][3] = MFMA(a1, b3, acc3[1][3]);
      }
    }
  }
#pragma unroll
  for (int t = 0; t < 2; ++t)
#pragma unroll
    for (int mt = 0; mt < 4; ++mt) {
      const int n3 = wv * 32 + t * 16 + g * 4;
      const int m = mt * 16 + l15;
      *(floatx4*)(out + (m0 + m) * 256 + n3) = acc3[t][mt];
    }
}

extern "C" void kernel_launch(void* const* d_in, const int* in_sizes, int n_in,
                              void* d_out, int out_size, void* d_ws, size_t ws_size,
                              hipStream_t stream) {
  const float* x = (const float*)d_in[0];
  const float* w1 = (const float*)d_in[1];
  const float* w2 = (const float*)d_in[2];
  const float* w3 = (const float*)d_in[3];
  float* out = (float*)d_out;
  const size_t M = 131072;

  u16* w1t = (u16*)d_ws;                      // [1024][256]
  u16* w2t = w1t + 1024 * 256;                // [1024][1024]
  u16* w3t = w2t + 1024 * 1024;               // [256][1024]
  u16* bufA = w3t + 256 * 1024;               // h1: CM x 1024 bf16
  const size_t weights_el = 1024 * 256 + 1024 * 1024 + 256 * 1024;

  size_t CM = 0;
  const size_t cands[4] = {32768, 16384, 8192, 4096};
  for (int i = 0; i < 4; ++i) {
    size_t need = (weights_el + 2 * cands[i] * 1024) * sizeof(u16);
    if (ws_size >= need) { CM = cands[i]; break; }
  }

  dim3 tb(32, 8);
  transpose_cvt<<<dim3(32, 8), tb, 0, stream>>>(w1, w1t, 256, 1024);
  transpose_cvt<<<dim3(32, 32), tb, 0, stream>>>(w2, w2t, 1024, 1024);
  transpose_cvt<<<dim3(8, 32), tb, 0, stream>>>(w3, w3t, 1024, 256);

  if (CM) {
    u16* bufB = bufA + CM * 1024;
    const int nchunk = (int)(M / CM);
    for (int ci = 0; ci < nchunk; ++ci) {
      const float* xc = x + (size_t)ci * CM * 256;
      float* oc = out + (size_t)ci * CM * 256;
      gemm2b<256, 0, true><<<(int)(CM / 128) * 4, 512, 0, stream>>>(xc, w1t, bufA, 1024, 4);
      gemm2b<1024, 0, false><<<(int)(CM / 128) * 4, 512, 0, stream>>>(bufA, w2t, bufB, 1024, 4);
      gemm2b<1024, 1, false><<<(int)(CM / 128), 512, 0, stream>>>(bufB, w3t, oc, 256, 1);
    }
  } else {
    mlp3_fused<<<M / 64, 512, 0, stream>>>(x, w1t, w2t, w3t, out);
  }
}

// Round 15
// 657.631 us; speedup vs baseline: 1.0851x; 1.0065x over previous
//
#include <hip/hip_runtime.h>

typedef __attribute__((ext_vector_type(8))) short short8;
typedef __attribute__((ext_vector_type(4))) float floatx4;
typedef __attribute__((ext_vector_type(2))) unsigned int uintx2;
typedef __attribute__((ext_vector_type(4))) unsigned int uintx4;
typedef unsigned short u16;

#define MFMA(a, b, c) __builtin_amdgcn_mfma_f32_16x16x32_bf16((a), (b), (c), 0, 0, 0)
#define BAR() do { asm volatile("" ::: "memory"); __builtin_amdgcn_s_barrier(); \
                   asm volatile("" ::: "memory"); } while (0)
#define LGKM0() asm volatile("s_waitcnt lgkmcnt(0)" ::: "memory")

__device__ __forceinline__ u16 f2bf(float f) {
  unsigned int u = __builtin_bit_cast(unsigned int, f);
  u += ((u >> 16) & 1u) + 0x7fffu;
  return (u16)(u >> 16);
}

__device__ __forceinline__ float softplus_f(float v) {
  float a = __builtin_fabsf(v);
  float e = __expf(-a);
  float l = __logf(1.0f + e);
  return __builtin_fmaxf(v, 0.0f) + l;
}

__device__ __forceinline__ unsigned int pack_sp(float lo, float hi) {
  return (unsigned int)f2bf(softplus_f(lo)) | ((unsigned int)f2bf(softplus_f(hi)) << 16);
}

// out[n*K + k] = bf16(in[k*N + n]); in is K x N row-major fp32
__global__ void transpose_cvt(const float* __restrict__ in, u16* __restrict__ out, int K, int N) {
  __shared__ float tile[32][33];
  const int bn = blockIdx.x * 32, bk = blockIdx.y * 32;
  const int tx = threadIdx.x, ty = threadIdx.y;  // 32 x 8
#pragma unroll
  for (int i = 0; i < 32; i += 8)
    tile[ty + i][tx] = in[(size_t)(bk + ty + i) * N + bn + tx];
  __syncthreads();
#pragma unroll
  for (int i = 0; i < 32; i += 8)
    out[(size_t)(bn + ty + i) * K + bk + tx] = f2bf(tile[tx][ty + i]);
}

__device__ __forceinline__ void gld16(const void* g, void* l) {
  __builtin_amdgcn_global_load_lds((const __attribute__((address_space(1))) void*)g,
                                   (__attribute__((address_space(3))) void*)l, 16, 0, 0);
}

template <int LN>
__device__ __forceinline__ void vwait() {
  if constexpr (LN == 0) asm volatile("s_waitcnt vmcnt(0)" ::: "memory");
  else if constexpr (LN == 2) asm volatile("s_waitcnt vmcnt(2)" ::: "memory");
  else if constexpr (LN == 4) asm volatile("s_waitcnt vmcnt(4)" ::: "memory");
}

// ===== m97-clone: 128x128 GEMM (C = act @ wt^T), BK=32, 4-wave blocks, =====
// ===== 32 KB LDS, target 3 blocks/CU (3 independent 4-wave barrier domains) =====
// Half layout: slot(r,gg) = r*4 + (gg ^ ((r>>1)&3)) -> conflict-free b128 frag
// reads, 64B-coalesced staging (A: 2 gld16/thread, W: 2).
// Per step: {stage(h+1) -> vwait<4> -> BAR -> 8 frag reads -> 16 MFMA -> BAR}.
template <int K, int EPI, bool ACTF32>
__global__ __launch_bounds__(256, 3) void gemm97(const void* __restrict__ actv,
                                                 const u16* __restrict__ wt,
                                                 void* __restrict__ Cout, int N, int nbn) {
  constexpr int H = K / 32;
  constexpr int BUF = 8192;  // u16 per buffer: A 4096 + W 4096 (16 KB); x2 = 32 KB
  __shared__ u16 lds[2 * BUF];
  u16* L = lds;
  const int tid = threadIdx.x, lane = tid & 63, wv = tid >> 6;  // 4 waves
  const int l15 = lane & 15, g = lane >> 4;
  const int wvm = wv >> 1, wvn = wv & 1;  // 2 x 2; wave owns 64m x 64n
  const int nwg = gridDim.x, o = blockIdx.x;
  const int sw = (o & 7) * (nwg >> 3) + (o >> 3);  // XCD swizzle (nwg % 8 == 0)
  const int bm = sw / nbn, bn = sw % nbn;
  const size_t am0 = (size_t)bm * 128;
  const size_t wn0 = (size_t)bn * 128;

  // fragment offsets (u16 units within a buffer)
  int afo[4], wfo[4];
#pragma unroll
  for (int mt = 0; mt < 4; ++mt) {
    const int r = wvm * 64 + mt * 16 + l15;
    afo[mt] = (r * 4 + (g ^ ((r >> 1) & 3))) * 8;
  }
#pragma unroll
  for (int nt = 0; nt < 4; ++nt) {
    const int r = wvn * 64 + nt * 16 + l15;
    wfo[nt] = 4096 + (r * 4 + (g ^ ((r >> 1) & 3))) * 8;
  }

  // staging: thread fills slots s = j*256 + tid (j=0,1) for A and for W
  int rS[2], gS[2];
#pragma unroll
  for (int j = 0; j < 2; ++j) {
    const int s = j * 256 + tid;
    rS[j] = s >> 2;
    gS[j] = (s & 3) ^ ((rS[j] >> 1) & 3);
  }
  const u16* asrc = nullptr;
  const float* fsrc = nullptr;
  if constexpr (ACTF32) fsrc = (const float*)actv + am0 * K;
  else asrc = (const u16*)actv + am0 * K;
  const u16* wsrc = wt + wn0 * K;

#define STG_W(hh)                                                                   \
  { _Pragma("unroll") for (int j = 0; j < 2; ++j)                                   \
      gld16(wsrc + (size_t)rS[j] * K + gS[j] * 8 + (hh) * 32,                       \
            L + ((hh) & 1) * BUF + 4096 + (j * 256 + tid) * 8); }
#define STG_AB(hh)                                                                  \
  { _Pragma("unroll") for (int j = 0; j < 2; ++j)                                   \
      gld16(asrc + (size_t)rS[j] * K + gS[j] * 8 + (hh) * 32,                       \
            L + ((hh) & 1) * BUF + (j * 256 + tid) * 8); }
#define STG_AF(hh)                                                                  \
  { floatx4 v0[2], v1[2];                                                           \
    _Pragma("unroll") for (int j = 0; j < 2; ++j) {                                 \
      const float* p_ = fsrc + (size_t)rS[j] * K + gS[j] * 8 + (hh) * 32;           \
      v0[j] = *(const floatx4*)p_;                                                  \
      v1[j] = *(const floatx4*)(p_ + 4);                                            \
    }                                                                               \
    _Pragma("unroll") for (int j = 0; j < 2; ++j) {                                 \
      uintx4 w_;                                                                    \
      w_.x = (unsigned)f2bf(v0[j].x) | ((unsigned)f2bf(v0[j].y) << 16);             \
      w_.y = (unsigned)f2bf(v0[j].z) | ((unsigned)f2bf(v0[j].w) << 16);             \
      w_.z = (unsigned)f2bf(v1[j].x) | ((unsigned)f2bf(v1[j].y) << 16);             \
      w_.w = (unsigned)f2bf(v1[j].z) | ((unsigned)f2bf(v1[j].w) << 16);             \
      *(uintx4*)(L + ((hh) & 1) * BUF + (j * 256 + tid) * 8) = w_;                  \
    } }

  floatx4 acc[4][4];
  const floatx4 z4 = {0.f, 0.f, 0.f, 0.f};
#pragma unroll
  for (int nt = 0; nt < 4; ++nt)
#pragma unroll
    for (int mt = 0; mt < 4; ++mt) acc[nt][mt] = z4;

  // prologue: stage step 0
  if constexpr (ACTF32) { STG_AF(0) STG_W(0) }
  else { STG_AB(0) STG_W(0) }

#pragma unroll 1
  for (int h = 0; h < H; ++h) {
    const int cb = (h & 1) * BUF;
    if (h + 1 < H) {
      if constexpr (ACTF32) { STG_AF(h + 1) STG_W(h + 1) LGKM0(); vwait<2>(); }
      else { STG_AB(h + 1) STG_W(h + 1) vwait<4>(); }
    } else {
      if constexpr (ACTF32) LGKM0();
      vwait<0>();
    }
    BAR();
    short8 af0 = *(const short8*)(L + cb + afo[0]);
    short8 af1 = *(const short8*)(L + cb + afo[1]);
    short8 af2 = *(const short8*)(L + cb + afo[2]);
    short8 af3 = *(const short8*)(L + cb + afo[3]);
    short8 wf0 = *(const short8*)(L + cb + wfo[0]);
    short8 wf1 = *(const short8*)(L + cb + wfo[1]);
    short8 wf2 = *(const short8*)(L + cb + wfo[2]);
    short8 wf3 = *(const short8*)(L + cb + wfo[3]);
    __builtin_amdgcn_s_setprio(1);
    acc[0][0] = MFMA(wf0, af0, acc[0][0]);
    acc[0][1] = MFMA(wf0, af1, acc[0][1]);
    acc[0][2] = MFMA(wf0, af2, acc[0][2]);
    acc[0][3] = MFMA(wf0, af3, acc[0][3]);
    acc[1][0] = MFMA(wf1, af0, acc[1][0]);
    acc[1][1] = MFMA(wf1, af1, acc[1][1]);
    acc[1][2] = MFMA(wf1, af2, acc[1][2]);
    acc[1][3] = MFMA(wf1, af3, acc[1][3]);
    acc[2][0] = MFMA(wf2, af0, acc[2][0]);
    acc[2][1] = MFMA(wf2, af1, acc[2][1]);
    acc[2][2] = MFMA(wf2, af2, acc[2][2]);
    acc[2][3] = MFMA(wf2, af3, acc[2][3]);
    acc[3][0] = MFMA(wf3, af0, acc[3][0]);
    acc[3][1] = MFMA(wf3, af1, acc[3][1]);
    acc[3][2] = MFMA(wf3, af2, acc[3][2]);
    acc[3][3] = MFMA(wf3, af3, acc[3][3]);
    __builtin_amdgcn_s_setprio(0);
    BAR();
  }
#undef STG_W
#undef STG_AB
#undef STG_AF

  __syncthreads();  // loop drained; LDS reusable

  if constexpr (EPI == 0) {
    // softplus -> bf16 C (128x128 = 32 KB) via LDS transpose, one pass
    u16* cl = L;
#pragma unroll
    for (int nt = 0; nt < 4; ++nt)
#pragma unroll
      for (int mt = 0; mt < 4; ++mt) {
        const int m = wvm * 64 + mt * 16 + l15;
        const int n0 = wvn * 64 + nt * 16 + g * 4;
        const int j = n0 >> 3, hh = (n0 >> 2) & 1;
        uintx2 pk;
        pk.x = pack_sp(acc[nt][mt].x, acc[nt][mt].y);
        pk.y = pack_sp(acc[nt][mt].z, acc[nt][mt].w);
        *(uintx2*)(cl + m * 128 + ((j ^ (m & 7)) << 3) + (hh << 2)) = pk;
      }
    __syncthreads();
    u16* outp = (u16*)Cout;
#pragma unroll
    for (int i = 0; i < 8; ++i) {
      const int c = i * 256 + tid;  // 16B chunk; 16/row, 128 rows
      const int m = c >> 4, j = c & 15;
      uintx4 v = *(const uintx4*)(cl + m * 128 + ((j ^ (m & 7)) << 3));
      *(uintx4*)(outp + (am0 + m) * N + wn0 + j * 8) = v;
    }
  } else {
    // fp32 C in two 64-row passes (32 KB each)
    float* cf = (float*)L;
#pragma unroll
    for (int q = 0; q < 2; ++q) {
      if (q) __syncthreads();
      if (wvm == q) {
#pragma unroll
        for (int nt = 0; nt < 4; ++nt)
#pragma unroll
          for (int mt = 0; mt < 4; ++mt) {
            const int m = mt * 16 + l15;  // 0..63
            const int p = (wvn * 64 + nt * 16 + g * 4) >> 1;  // even 2-float slot
            *(floatx4*)(cf + m * 128 + ((p ^ ((m & 7) << 1)) << 1)) = acc[nt][mt];
          }
      }
      __syncthreads();
      float* outp = (float*)Cout;
#pragma unroll
      for (int i = 0; i < 8; ++i) {
        const int c = i * 256 + tid;  // 16B chunk; 32/row, 64 rows
        const int m = c >> 5, cc = c & 31;
        const int p = cc * 2;
        floatx4 v = *(const floatx4*)(cf + m * 128 + ((p ^ ((m & 7) << 1)) << 1));
        *(floatx4*)(outp + (am0 + q * 64 + m) * N + wn0 + cc * 4) = v;
      }
    }
  }
}

// ---------------- fallback: R1 fused kernel (ws too small) ----------------
__global__ __launch_bounds__(512, 2) void mlp3_fused(const float* __restrict__ x,
                                                     const u16* __restrict__ w1t,
                                                     const u16* __restrict__ w2t,
                                                     const u16* __restrict__ w3t,
                                                     float* __restrict__ out) {
  __shared__ u16 h1s[64 * 1024];
  __shared__ u16 xs[64 * 256];
  const int tid = threadIdx.x, lane = tid & 63, wv = tid >> 6;
  const int l15 = lane & 15, g = lane >> 4;
  const size_t m0 = (size_t)blockIdx.x * 64;
  const floatx4 z4 = {0.f, 0.f, 0.f, 0.f};
  {
    const float* xp = x + m0 * 256;
#pragma unroll
    for (int r = 0; r < 8; ++r) {
      int idx4 = r * 512 + tid;
      int m = idx4 >> 6, k = (idx4 & 63) << 2;
      floatx4 v = *(const floatx4*)(xp + m * 256 + k);
      uintx2 pk;
      pk.x = (unsigned)f2bf(v.x) | ((unsigned)f2bf(v.y) << 16);
      pk.y = (unsigned)f2bf(v.z) | ((unsigned)f2bf(v.w) << 16);
      *(uintx2*)(xs + ((m * 256 + k) ^ ((m & 7) << 3))) = pk;
    }
  }
  __syncthreads();
#pragma unroll 1
  for (int c = 0; c < 4; ++c) {
    floatx4 acc[2][4];
#pragma unroll
    for (int t = 0; t < 2; ++t)
#pragma unroll
      for (int mt = 0; mt < 4; ++mt) acc[t][mt] = z4;
    const u16* p0 = w1t + (size_t)(c * 256 + wv * 32 + l15) * 256;
#pragma unroll
    for (int ks = 0; ks < 8; ++ks) {
      const int k = ks * 32 + g * 8;
      short8 a0 = *(const short8*)(p0 + k);
      short8 a1 = *(const short8*)(p0 + 16 * 256 + k);
      short8 b0 = *(const short8*)(xs + (((0 * 16 + l15) * 256 + k) ^ ((l15 & 7) << 3)));
      short8 b1 = *(const short8*)(xs + (((1 * 16 + l15) * 256 + k) ^ ((l15 & 7) << 3)));
      short8 b2 = *(const short8*)(xs + (((2 * 16 + l15) * 256 + k) ^ ((l15 & 7) << 3)));
      short8 b3 = *(const short8*)(xs + (((3 * 16 + l15) * 256 + k) ^ ((l15 & 7) << 3)));
      acc[0][0] = MFMA(a0, b0, acc[0][0]); acc[0][1] = MFMA(a0, b1, acc[0][1]);
      acc[0][2] = MFMA(a0, b2, acc[0][2]); acc[0][3] = MFMA(a0, b3, acc[0][3]);
      acc[1][0] = MFMA(a1, b0, acc[1][0]); acc[1][1] = MFMA(a1, b1, acc[1][1]);
      acc[1][2] = MFMA(a1, b2, acc[1][2]); acc[1][3] = MFMA(a1, b3, acc[1][3]);
    }
#pragma unroll
    for (int t = 0; t < 2; ++t)
#pragma unroll
      for (int mt = 0; mt < 4; ++mt) {
        const int n1 = c * 256 + wv * 32 + t * 16 + g * 4;
        const int m = mt * 16 + l15;
        uintx2 pk;
        pk.x = pack_sp(acc[t][mt].x, acc[t][mt].y);
        pk.y = pack_sp(acc[t][mt].z, acc[t][mt].w);
        *(uintx2*)(h1s + ((m * 1024 + n1) ^ ((m & 7) << 3))) = pk;
      }
  }
  __syncthreads();
  floatx4 acc3[2][4];
#pragma unroll
  for (int t = 0; t < 2; ++t)
#pragma unroll
    for (int mt = 0; mt < 4; ++mt) acc3[t][mt] = z4;
#pragma unroll 1
  for (int c2 = 0; c2 < 4; ++c2) {
    floatx4 acc2[2][4];
#pragma unroll
    for (int t = 0; t < 2; ++t)
#pragma unroll
      for (int mt = 0; mt < 4; ++mt) acc2[t][mt] = z4;
    {
      const u16* p0 = w2t + (size_t)(c2 * 256 + wv * 32 + l15) * 1024;
#pragma unroll 4
      for (int ks = 0; ks < 32; ++ks) {
        const int k = ks * 32 + g * 8;
        short8 a0 = *(const short8*)(p0 + k);
        short8 a1 = *(const short8*)(p0 + 16 * 1024 + k);
        short8 b0 = *(const short8*)(h1s + (((0 * 16 + l15) * 1024 + k) ^ ((l15 & 7) << 3)));
        short8 b1 = *(const short8*)(h1s + (((1 * 16 + l15) * 1024 + k) ^ ((l15 & 7) << 3)));
        short8 b2 = *(const short8*)(h1s + (((2 * 16 + l15) * 1024 + k) ^ ((l15 & 7) << 3)));
        short8 b3 = *(const short8*)(h1s + (((3 * 16 + l15) * 1024 + k) ^ ((l15 & 7) << 3)));
        acc2[0][0] = MFMA(a0, b0, acc2[0][0]); acc2[0][1] = MFMA(a0, b1, acc2[0][1]);
        acc2[0][2] = MFMA(a0, b2, acc2[0][2]); acc2[0][3] = MFMA(a0, b3, acc2[0][3]);
        acc2[1][0] = MFMA(a1, b0, acc2[1][0]); acc2[1][1] = MFMA(a1, b1, acc2[1][1]);
        acc2[1][2] = MFMA(a1, b2, acc2[1][2]); acc2[1][3] = MFMA(a1, b3, acc2[1][3]);
      }
    }
    __syncthreads();
#pragma unroll
    for (int t = 0; t < 2; ++t)
#pragma unroll
      for (int mt = 0; mt < 4; ++mt) {
        const int n2l = wv * 32 + t * 16 + g * 4;
        const int m = mt * 16 + l15;
        uintx2 pk;
        pk.x = pack_sp(acc2[t][mt].x, acc2[t][mt].y);
        pk.y = pack_sp(acc2[t][mt].z, acc2[t][mt].w);
        *(uintx2*)(xs + ((m * 256 + n2l) ^ ((m & 7) << 3))) = pk;
      }
    __syncthreads();
    {
      const u16* p0 = w3t + (size_t)(wv * 32 + l15) * 1024 + c2 * 256;
#pragma unroll
      for (int ks = 0; ks < 8; ++ks) {
        const int k = ks * 32 + g * 8;
        short8 a0 = *(const short8*)(p0 + k);
        short8 a1 = *(const short8*)(p0 + 16 * 1024 + k);
        short8 b0 = *(const short8*)(xs + (((0 * 16 + l15) * 256 + k) ^ ((l15 & 7) << 3)));
        short8 b1 = *(const short8*)(xs + (((1 * 16 + l15) * 256 + k) ^ ((l15 & 7) << 3)));
        short8 b2 = *(const short8*)(xs + (((2 * 16 + l15) * 256 + k) ^ ((l15 & 7) << 3)));
        short8 b3 = *(const short8*)(xs + (((3 * 16 + l15) * 256 + k) ^ ((l15 & 7) << 3)));
        acc3[0][0] = MFMA(a0, b0, acc3[0][0]); acc3[0][1] = MFMA(a0, b1, acc3[0][1]);
        acc3[0][2] = MFMA(a0, b2, acc3[0][2]); acc3[0][3] = MFMA(a0, b3, acc3[0][3]);
        acc3[1][0] = MFMA(a1, b0, acc3[1][0]); acc3[1][1] = MFMA(a1, b1, acc3[1][1]);
        acc3[1][2] = MFMA(a1, b2, acc3[1][2]); acc3[1][3] = MFMA(a1, b3, acc3[1][3]);
      }
    }
  }
#pragma unroll
  for (int t = 0; t < 2; ++t)
#pragma unroll
    for (int mt = 0; mt < 4; ++mt) {
      const int n3 = wv * 32 + t * 16 + g * 4;
      const int m = mt * 16 + l15;
      *(floatx4*)(out + (m0 + m) * 256 + n3) = acc3[t][mt];
    }
}

extern "C" void kernel_launch(void* const* d_in, const int* in_sizes, int n_in,
                              void* d_out, int out_size, void* d_ws, size_t ws_size,
                              hipStream_t stream) {
  const float* x = (const float*)d_in[0];
  const float* w1 = (const float*)d_in[1];
  const float* w2 = (const float*)d_in[2];
  const float* w3 = (const float*)d_in[3];
  float* out = (float*)d_out;
  const size_t M = 131072;

  u16* w1t = (u16*)d_ws;                      // [1024][256]
  u16* w2t = w1t + 1024 * 256;                // [1024][1024]
  u16* w3t = w2t + 1024 * 1024;               // [256][1024]
  u16* bufA = w3t + 256 * 1024;               // h1: CM x 1024 bf16
  const size_t weights_el = 1024 * 256 + 1024 * 1024 + 256 * 1024;

  size_t CM = 0;
  const size_t cands[4] = {32768, 16384, 8192, 4096};
  for (int i = 0; i < 4; ++i) {
    size_t need = (weights_el + 2 * cands[i] * 1024) * sizeof(u16);
    if (ws_size >= need) { CM = cands[i]; break; }
  }

  dim3 tb(32, 8);
  transpose_cvt<<<dim3(32, 8), tb, 0, stream>>>(w1, w1t, 256, 1024);
  transpose_cvt<<<dim3(32, 32), tb, 0, stream>>>(w2, w2t, 1024, 1024);
  transpose_cvt<<<dim3(8, 32), tb, 0, stream>>>(w3, w3t, 1024, 256);

  if (CM) {
    u16* bufB = bufA + CM * 1024;
    const int nchunk = (int)(M / CM);
    for (int ci = 0; ci < nchunk; ++ci) {
      const float* xc = x + (size_t)ci * CM * 256;
      float* oc = out + (size_t)ci * CM * 256;
      gemm97<256, 0, true><<<(int)(CM / 128) * 8, 256, 0, stream>>>(xc, w1t, bufA, 1024, 8);
      gemm97<1024, 0, false><<<(int)(CM / 128) * 8, 256, 0, stream>>>(bufA, w2t, bufB, 1024, 8);
      gemm97<1024, 1, false><<<(int)(CM / 128) * 2, 256, 0, stream>>>(bufB, w3t, oc, 256, 2);
    }
  } else {
    mlp3_fused<<<M / 64, 512, 0, stream>>>(x, w1t, w2t, w3t, out);
  }
}